// Round 16
// baseline (434.956 us; speedup 1.0000x reference)
//
#include <hip/hip_runtime.h>
#include <hip/hip_fp16.h>
#include <hip/hip_cooperative_groups.h>
#include <math.h>

namespace cg = cooperative_groups;

#define TSTEPS 6
#define NN 20000
#define NE 320000
#define INF 11
#define XPAD 16
#define HID 64
#define OUTF 3
#define NPW 4                     // nodes per wave in fallback fused kernels
#define CNPW 5                    // nodes per wave in cooperative mega-kernel
#define CNBLK 1000                // 1000 blocks x 4 waves x 5 nodes = 20000
#define EPMAX (NE + 7 * NN)       // CSR slots after pad-to-8
#define NB ((NN + 255) / 256)     // scan blocks = 79

__device__ __forceinline__ float bcast(float v, int l) {
    return __uint_as_float(__builtin_amdgcn_readlane(__float_as_uint(v), l));
}

__device__ __forceinline__ float tanh_safe(float a) {
    float e2 = __expf(-2.0f * fabsf(a));
    float t = (1.0f - e2) / (1.0f + e2);
    return copysignf(t, a);
}

// ---------------- setup kernels (once per call) ----------------

__global__ void k_cnt(const int* __restrict__ src, const int* __restrict__ dst,
                      int* __restrict__ degi, int* __restrict__ indeg, int E) {
    int e = blockIdx.x * blockDim.x + threadIdx.x;
    if (e >= E) return;
    atomicAdd(&degi[src[e]], 1);
    atomicAdd(&indeg[dst[e]], 1);
}

__global__ __launch_bounds__(256) void k_scanA(const int* __restrict__ indeg,
                                               int* __restrict__ part,
                                               int* __restrict__ bsum, int n) {
    int idx = blockIdx.x * 256 + threadIdx.x;
    int lane = threadIdx.x & 63, wv = threadIdx.x >> 6;
    int v = (idx < n) ? ((indeg[idx] + 7) & ~7) : 0;
#pragma unroll
    for (int off = 1; off < 64; off <<= 1) {
        int t = __shfl_up(v, off);
        if (lane >= off) v += t;
    }
    __shared__ int wsum[4];
    if (lane == 63) wsum[wv] = v;
    __syncthreads();
    int add = 0;
    for (int w = 0; w < wv; ++w) add += wsum[w];
    v += add;
    if (idx < n) part[idx] = v;
    if (threadIdx.x == 255) bsum[blockIdx.x] = v;
}

__global__ __launch_bounds__(128) void k_scanB(const int* __restrict__ bsum,
                                               int* __restrict__ boff, int nb) {
    int tid = threadIdx.x;
    int lane = tid & 63, wv = tid >> 6;
    int orig = (tid < nb) ? bsum[tid] : 0;
    int v = orig;
#pragma unroll
    for (int off = 1; off < 64; off <<= 1) {
        int t = __shfl_up(v, off);
        if (lane >= off) v += t;
    }
    __shared__ int w0;
    if (lane == 63 && wv == 0) w0 = v;
    __syncthreads();
    if (wv == 1) v += w0;
    if (tid < nb) boff[tid] = v - orig;  // exclusive
}

__global__ __launch_bounds__(256) void k_scanC(const int* __restrict__ indeg,
                                               int* __restrict__ part,
                                               const int* __restrict__ boff,
                                               int* __restrict__ cursor, int n) {
    int idx = blockIdx.x * 256 + threadIdx.x;
    if (idx >= n) return;
    int pd = (indeg[idx] + 7) & ~7;
    int incl = part[idx] + boff[blockIdx.x];
    int excl = incl - pd;
    part[idx] = excl;      // part aliases rowstart
    cursor[idx] = excl;
    if (idx == n - 1) part[n] = incl;
}

__global__ void k_fill(const int* __restrict__ src, const int* __restrict__ dst,
                       const int* __restrict__ degi, int* __restrict__ cursor,
                       int2* __restrict__ pack, int E) {
    int e = blockIdx.x * blockDim.x + threadIdx.x;
    if (e >= E) return;
    int s = src[e], d = dst[e];
    float ds = (float)degi[s];
    float dd = (float)degi[d];
    float ns = ds > 0.0f ? rsqrtf(fmaxf(ds, 1.0f)) : 0.0f;
    float nd = dd > 0.0f ? rsqrtf(fmaxf(dd, 1.0f)) : 0.0f;
    int pos = atomicAdd(&cursor[d], 1);
    int2 v;
    v.x = s;
    v.y = __float_as_int(-ns * nd);
    pack[pos] = v;
}

__global__ void k_init(const float* __restrict__ Wh, const float* __restrict__ Wx,
                       float4* __restrict__ Wh4, float2* __restrict__ Wh2,
                       float4* __restrict__ Wx4, float2* __restrict__ Wx2,
                       float* __restrict__ h, __half* __restrict__ h16,
                       const float* __restrict__ Xt, float* __restrict__ xin,
                       __half* __restrict__ xin16) {
    int idx = blockIdx.x * blockDim.x + threadIdx.x;
    if (idx < NN * HID) { h[idx] = 0.0f; h16[idx] = __float2half(0.0f); }
    if (idx < HID * HID) {
        int j = idx >> 6, f = idx & 63;
        float4 v4;
        v4.x = Wh[((0 * 2 + 0) * HID + j) * HID + f];
        v4.y = Wh[((0 * 2 + 1) * HID + j) * HID + f];
        v4.z = Wh[((1 * 2 + 0) * HID + j) * HID + f];
        v4.w = Wh[((1 * 2 + 1) * HID + j) * HID + f];
        Wh4[idx] = v4;
        float2 v2;
        v2.x = Wh[((2 * 2 + 0) * HID + j) * HID + f];
        v2.y = Wh[((2 * 2 + 1) * HID + j) * HID + f];
        Wh2[idx] = v2;
    } else if (idx < HID * HID + INF * HID) {
        int k = idx - HID * HID;
        int i = k >> 6, f = k & 63;
        float4 v4;
        v4.x = Wx[((0 * 2 + 0) * INF + i) * HID + f];
        v4.y = Wx[((0 * 2 + 1) * INF + i) * HID + f];
        v4.z = Wx[((1 * 2 + 0) * INF + i) * HID + f];
        v4.w = Wx[((1 * 2 + 1) * INF + i) * HID + f];
        Wx4[k] = v4;
        float2 v2;
        v2.x = Wx[((2 * 2 + 0) * INF + i) * HID + f];
        v2.y = Wx[((2 * 2 + 1) * INF + i) * HID + f];
        Wx2[k] = v2;
    }
    if (idx < NN) {
        const float* xt = Xt + (size_t)idx * INF;
        float* xo = xin + (size_t)idx * XPAD;
        __half* xh = xin16 + (size_t)idx * XPAD;
#pragma unroll
        for (int k = 0; k < INF; ++k) { float v = xt[k]; xo[k] = v; xh[k] = __float2half(v); }
#pragma unroll
        for (int k = INF; k < XPAD; ++k) { xo[k] = 0.0f; xh[k] = __float2half(0.0f); }
    }
}

// ---------------- fallback fused per-timestep kernels (round-15, proven) ----------------

__global__ __launch_bounds__(256) void k_gz(
    const int* __restrict__ rowstart, const int2* __restrict__ pack,
    const float* __restrict__ xin, const __half* __restrict__ xin16,
    const __half* __restrict__ h16,
    const float4* __restrict__ Wx4, const float* __restrict__ bx,
    const float4* __restrict__ Wh4, const float* __restrict__ bh,
    float* __restrict__ t1x, __half* __restrict__ Zb16,
    __half* __restrict__ hr16, int n) {
    int wid = __builtin_amdgcn_readfirstlane(
        (int)((blockIdx.x * blockDim.x + threadIdx.x) >> 6));
    int wbase = wid * NPW;
    int lane = threadIdx.x & 63;
    int f16i = lane & 15, eo = lane >> 4;
    if (wbase >= n) return;

    int ps[NPW], es[NPW];
    float A0[NPW], A1[NPW], C0[NPW], C1[NPW];
    float thg[NPW], axv[NPW], hv[NPW];
#pragma unroll
    for (int nn = 0; nn < NPW; ++nn) {
        int node = wbase + nn;
        ps[nn] = rowstart[node];
        es[nn] = rowstart[node + 1];
        hv[nn] = __half2float(h16[(size_t)node * HID + lane]);
        A0[nn] = 0.0f; A1[nn] = 0.0f; C0[nn] = 0.0f; C1[nn] = 0.0f;
    }
    while ((ps[0] < es[0]) | (ps[1] < es[1]) | (ps[2] < es[2]) | (ps[3] < es[3])) {
#pragma unroll
        for (int nn = 0; nn < NPW; ++nn) {
            bool act = ps[nn] < es[nn];
            int q = act ? ps[nn] : 0;
            float m = act ? 1.0f : 0.0f;
            int2 q0 = pack[q],     q1 = pack[q + 1], q2 = pack[q + 2], q3 = pack[q + 3];
            int2 q4 = pack[q + 4], q5 = pack[q + 5], q6 = pack[q + 6], q7 = pack[q + 7];
            float w0 = __int_as_float(q0.y) * m, w1 = __int_as_float(q1.y) * m;
            float w2 = __int_as_float(q2.y) * m, w3 = __int_as_float(q3.y) * m;
            float w4 = __int_as_float(q4.y) * m, w5 = __int_as_float(q5.y) * m;
            float w6 = __int_as_float(q6.y) * m, w7 = __int_as_float(q7.y) * m;
            A0[nn] = fmaf(w0, __half2float(h16[(size_t)q0.x * HID + lane]), A0[nn]);
            A1[nn] = fmaf(w1, __half2float(h16[(size_t)q1.x * HID + lane]), A1[nn]);
            A0[nn] = fmaf(w2, __half2float(h16[(size_t)q2.x * HID + lane]), A0[nn]);
            A1[nn] = fmaf(w3, __half2float(h16[(size_t)q3.x * HID + lane]), A1[nn]);
            A0[nn] = fmaf(w4, __half2float(h16[(size_t)q4.x * HID + lane]), A0[nn]);
            A1[nn] = fmaf(w5, __half2float(h16[(size_t)q5.x * HID + lane]), A1[nn]);
            A0[nn] = fmaf(w6, __half2float(h16[(size_t)q6.x * HID + lane]), A0[nn]);
            A1[nn] = fmaf(w7, __half2float(h16[(size_t)q7.x * HID + lane]), A1[nn]);
            int2 x0 = pack[q + 2 * eo], x1 = pack[q + 2 * eo + 1];
            C0[nn] = fmaf(__int_as_float(x0.y) * m,
                          __half2float(xin16[(size_t)x0.x * XPAD + f16i]), C0[nn]);
            C1[nn] = fmaf(__int_as_float(x1.y) * m,
                          __half2float(xin16[(size_t)x1.x * XPAD + f16i]), C1[nn]);
            ps[nn] += 8;
        }
    }
#pragma unroll
    for (int nn = 0; nn < NPW; ++nn) {
        thg[nn] = A0[nn] + A1[nn];
        float cx = C0[nn] + C1[nn];
        cx += __shfl_down(cx, 32);
        cx += __shfl_down(cx, 16);
        axv[nn] = cx;
    }
#pragma unroll
    for (int nn = 0; nn < NPW; ++nn)
        if (lane < 16) t1x[(size_t)(wbase + nn) * XPAD + lane] = axv[nn];

    float xrow = xin[(size_t)wbase * XPAD + lane];
    float b0z = bx[0 * HID + lane] + bh[0 * HID + lane];
    float b0r = bx[1 * HID + lane] + bh[1 * HID + lane];
    float az[NPW], ar[NPW];
#pragma unroll
    for (int nn = 0; nn < NPW; ++nn) { az[nn] = b0z; ar[nn] = b0r; }
#pragma unroll
    for (int i = 0; i < INF; ++i) {
        float4 w = Wx4[i * HID + lane];
#pragma unroll
        for (int nn = 0; nn < NPW; ++nn) {
            float xv = bcast(xrow, nn * XPAD + i);
            float tv = bcast(axv[nn], i);
            az[nn] = fmaf(xv, w.x, fmaf(tv, w.y, az[nn]));
            ar[nn] = fmaf(xv, w.z, fmaf(tv, w.w, ar[nn]));
        }
    }
#pragma unroll 8
    for (int j = 0; j < HID; ++j) {
        float4 w = Wh4[j * HID + lane];
#pragma unroll
        for (int nn = 0; nn < NPW; ++nn) {
            float hj = bcast(hv[nn], j);
            float tj = bcast(thg[nn], j);
            az[nn] = fmaf(hj, w.x, fmaf(tj, w.y, az[nn]));
            ar[nn] = fmaf(hj, w.z, fmaf(tj, w.w, ar[nn]));
        }
    }
#pragma unroll
    for (int nn = 0; nn < NPW; ++nn) {
        int node = wbase + nn;
        float Z = 1.0f / (1.0f + __expf(-az[nn]));
        float R = 1.0f / (1.0f + __expf(-ar[nn]));
        Zb16[(size_t)node * HID + lane] = __float2half(Z);
        hr16[(size_t)node * HID + lane] = __float2half(hv[nn] * R);
    }
}

__global__ __launch_bounds__(256) void k_gc(
    const int* __restrict__ rowstart, const int2* __restrict__ pack,
    const float* __restrict__ xin, const float* __restrict__ t1x,
    float* __restrict__ h, __half* __restrict__ h16,
    const __half* __restrict__ hr16,
    const float2* __restrict__ Wx2, const float* __restrict__ bx,
    const float2* __restrict__ Wh2, const float* __restrict__ bh,
    const __half* __restrict__ Zb16,
    const float* __restrict__ hw, const float* __restrict__ hb,
    float* __restrict__ out,
    const float* __restrict__ Xcur, const float* __restrict__ Xnxt,
    float* __restrict__ xin_w, __half* __restrict__ xin16_w,
    int last, int n) {
    int wid = __builtin_amdgcn_readfirstlane(
        (int)((blockIdx.x * blockDim.x + threadIdx.x) >> 6));
    int wbase = wid * NPW;
    int lane = threadIdx.x & 63;
    if (wbase >= n) return;

    int ps[NPW], es[NPW];
    float A0[NPW], A1[NPW];
    float thg[NPW], hrv[NPW];
#pragma unroll
    for (int nn = 0; nn < NPW; ++nn) {
        int node = wbase + nn;
        ps[nn] = rowstart[node];
        es[nn] = rowstart[node + 1];
        hrv[nn] = __half2float(hr16[(size_t)node * HID + lane]);
        A0[nn] = 0.0f; A1[nn] = 0.0f;
    }
    while ((ps[0] < es[0]) | (ps[1] < es[1]) | (ps[2] < es[2]) | (ps[3] < es[3])) {
#pragma unroll
        for (int nn = 0; nn < NPW; ++nn) {
            bool act = ps[nn] < es[nn];
            int q = act ? ps[nn] : 0;
            float m = act ? 1.0f : 0.0f;
            int2 q0 = pack[q],     q1 = pack[q + 1], q2 = pack[q + 2], q3 = pack[q + 3];
            int2 q4 = pack[q + 4], q5 = pack[q + 5], q6 = pack[q + 6], q7 = pack[q + 7];
            A0[nn] = fmaf(__int_as_float(q0.y) * m,
                          __half2float(hr16[(size_t)q0.x * HID + lane]), A0[nn]);
            A1[nn] = fmaf(__int_as_float(q1.y) * m,
                          __half2float(hr16[(size_t)q1.x * HID + lane]), A1[nn]);
            A0[nn] = fmaf(__int_as_float(q2.y) * m,
                          __half2float(hr16[(size_t)q2.x * HID + lane]), A0[nn]);
            A1[nn] = fmaf(__int_as_float(q3.y) * m,
                          __half2float(hr16[(size_t)q3.x * HID + lane]), A1[nn]);
            A0[nn] = fmaf(__int_as_float(q4.y) * m,
                          __half2float(hr16[(size_t)q4.x * HID + lane]), A0[nn]);
            A1[nn] = fmaf(__int_as_float(q5.y) * m,
                          __half2float(hr16[(size_t)q5.x * HID + lane]), A1[nn]);
            A0[nn] = fmaf(__int_as_float(q6.y) * m,
                          __half2float(hr16[(size_t)q6.x * HID + lane]), A0[nn]);
            A1[nn] = fmaf(__int_as_float(q7.y) * m,
                          __half2float(hr16[(size_t)q7.x * HID + lane]), A1[nn]);
            ps[nn] += 8;
        }
    }
#pragma unroll
    for (int nn = 0; nn < NPW; ++nn) thg[nn] = A0[nn] + A1[nn];

    float xrow = xin[(size_t)wbase * XPAD + lane];
    float trow = t1x[(size_t)wbase * XPAD + lane];
    float b0 = bx[2 * HID + lane] + bh[2 * HID + lane];
    float ah[NPW];
#pragma unroll
    for (int nn = 0; nn < NPW; ++nn) ah[nn] = b0;
#pragma unroll
    for (int i = 0; i < INF; ++i) {
        float2 w = Wx2[i * HID + lane];
#pragma unroll
        for (int nn = 0; nn < NPW; ++nn) {
            float xv = bcast(xrow, nn * XPAD + i);
            float tv = bcast(trow, nn * XPAD + i);
            ah[nn] = fmaf(xv, w.x, fmaf(tv, w.y, ah[nn]));
        }
    }
#pragma unroll 8
    for (int j = 0; j < HID; ++j) {
        float2 w = Wh2[j * HID + lane];
#pragma unroll
        for (int nn = 0; nn < NPW; ++nn) {
            float hj = bcast(hrv[nn], j);
            float tj = bcast(thg[nn], j);
            ah[nn] = fmaf(hj, w.x, fmaf(tj, w.y, ah[nn]));
        }
    }
#pragma unroll
    for (int nn = 0; nn < NPW; ++nn) {
        int node = wbase + nn;
        float Ht = tanh_safe(ah[nn]);
        float z = __half2float(Zb16[(size_t)node * HID + lane]);
        float hvv = h[(size_t)node * HID + lane];
        float hnew = z * hvv + (1.0f - z) * Ht;
        h[(size_t)node * HID + lane] = hnew;
        h16[(size_t)node * HID + lane] = __float2half(hnew);
        float u0, u1, u2;
        {
            float v0 = hnew * hw[lane * OUTF + 0];
            float v1 = hnew * hw[lane * OUTF + 1];
            float v2 = hnew * hw[lane * OUTF + 2];
            for (int off = 32; off; off >>= 1) {
                v0 += __shfl_down(v0, off);
                v1 += __shfl_down(v1, off);
                v2 += __shfl_down(v2, off);
            }
            u0 = bcast(v0, 0) + hb[0];
            u1 = bcast(v1, 0) + hb[1];
            u2 = bcast(v2, 0) + hb[2];
        }
        if (lane == 0) {
            float* o = out + (size_t)node * OUTF;
            o[0] = u0; o[1] = u1; o[2] = u2;
        }
        if (!last) {
            const float* x1r = Xnxt + (size_t)node * INF;
            const float* x0r = Xcur + (size_t)node * INF;
            float x1 = (lane < INF) ? x1r[lane] : 0.0f;
            float x0v = (lane >= 3 && lane < 7) ? x0r[lane] : 0.0f;
            float dt = bcast(x1, 6) - bcast(x0v, 6);
            float inv = 1.0f / dt;
            float c3 = bcast(x0v, 3), c4 = bcast(x0v, 4), c5 = bcast(x0v, 5);
            float val;
            if (lane < 3) val = x1;
            else if (lane < 6) val = (lane == 3) ? u0 : (lane == 4) ? u1 : u2;
            else if (lane < 8) val = x1;
            else if (lane < 11) {
                float uu = (lane == 8) ? u0 : (lane == 9) ? u1 : u2;
                float cc = (lane == 8) ? c3 : (lane == 9) ? c4 : c5;
                val = (uu - cc) * inv;
            } else val = 0.0f;
            if (lane < XPAD) {
                xin_w[(size_t)node * XPAD + lane] = val;
                xin16_w[(size_t)node * XPAD + lane] = __float2half(val);
            }
        }
    }
}

// ---------------- cooperative mega-kernel (minimal cross-phase state) ----------------
// 1000 blocks x 256 thr (4 waves) x CNPW=5 nodes = 20000. Persistent regs across
// phases: h32[5], zz[5] only. t1x via memory (as fallback); own-hr reloaded from hr16.
__global__ __launch_bounds__(256, 4) void k_loop(
    const int* __restrict__ rowstart, const int2* __restrict__ pack,
    const float* __restrict__ X_seq,
    float* __restrict__ xin, __half* __restrict__ xin16,
    __half* __restrict__ h16, __half* __restrict__ hr16,
    float* __restrict__ t1x,
    const float4* __restrict__ Wx4, const float2* __restrict__ Wx2,
    const float* __restrict__ bx,
    const float4* __restrict__ Wh4, const float2* __restrict__ Wh2,
    const float* __restrict__ bh,
    const float* __restrict__ hw, const float* __restrict__ hb,
    float* __restrict__ out) {
    cg::grid_group grid = cg::this_grid();
    int wid = __builtin_amdgcn_readfirstlane(
        (int)((blockIdx.x * blockDim.x + threadIdx.x) >> 6));
    int wbase = wid * CNPW;
    int lane = threadIdx.x & 63;
    int f16i = lane & 15, eo = lane >> 4;

    int ps0[CNPW], es0[CNPW];
#pragma unroll
    for (int nn = 0; nn < CNPW; ++nn) {
        ps0[nn] = rowstart[wbase + nn];
        es0[nn] = rowstart[wbase + nn + 1];
    }
    float h32[CNPW], zz[CNPW];
#pragma unroll
    for (int nn = 0; nn < CNPW; ++nn) h32[nn] = 0.0f;

    for (int t = 0; t < TSTEPS; ++t) {
        // ---- phase A: gathers + Z/R dense; writes hr16 + t1x ----
        {
            int ps[CNPW];
            float A0[CNPW], A1[CNPW], C0[CNPW], C1[CNPW];
#pragma unroll
            for (int nn = 0; nn < CNPW; ++nn) {
                ps[nn] = ps0[nn];
                A0[nn] = 0.0f; A1[nn] = 0.0f; C0[nn] = 0.0f; C1[nn] = 0.0f;
            }
            while ((ps[0] < es0[0]) | (ps[1] < es0[1]) | (ps[2] < es0[2]) |
                   (ps[3] < es0[3]) | (ps[4] < es0[4])) {
#pragma unroll
                for (int nn = 0; nn < CNPW; ++nn) {
                    bool act = ps[nn] < es0[nn];
                    int q = act ? ps[nn] : 0;
                    float m = act ? 1.0f : 0.0f;
                    int2 q0 = pack[q],     q1 = pack[q + 1], q2 = pack[q + 2], q3 = pack[q + 3];
                    int2 q4 = pack[q + 4], q5 = pack[q + 5], q6 = pack[q + 6], q7 = pack[q + 7];
                    float w0 = __int_as_float(q0.y) * m, w1 = __int_as_float(q1.y) * m;
                    float w2 = __int_as_float(q2.y) * m, w3 = __int_as_float(q3.y) * m;
                    float w4 = __int_as_float(q4.y) * m, w5 = __int_as_float(q5.y) * m;
                    float w6 = __int_as_float(q6.y) * m, w7 = __int_as_float(q7.y) * m;
                    A0[nn] = fmaf(w0, __half2float(h16[(size_t)q0.x * HID + lane]), A0[nn]);
                    A1[nn] = fmaf(w1, __half2float(h16[(size_t)q1.x * HID + lane]), A1[nn]);
                    A0[nn] = fmaf(w2, __half2float(h16[(size_t)q2.x * HID + lane]), A0[nn]);
                    A1[nn] = fmaf(w3, __half2float(h16[(size_t)q3.x * HID + lane]), A1[nn]);
                    A0[nn] = fmaf(w4, __half2float(h16[(size_t)q4.x * HID + lane]), A0[nn]);
                    A1[nn] = fmaf(w5, __half2float(h16[(size_t)q5.x * HID + lane]), A1[nn]);
                    A0[nn] = fmaf(w6, __half2float(h16[(size_t)q6.x * HID + lane]), A0[nn]);
                    A1[nn] = fmaf(w7, __half2float(h16[(size_t)q7.x * HID + lane]), A1[nn]);
                    int2 x0 = pack[q + 2 * eo], x1 = pack[q + 2 * eo + 1];
                    C0[nn] = fmaf(__int_as_float(x0.y) * m,
                                  __half2float(xin16[(size_t)x0.x * XPAD + f16i]), C0[nn]);
                    C1[nn] = fmaf(__int_as_float(x1.y) * m,
                                  __half2float(xin16[(size_t)x1.x * XPAD + f16i]), C1[nn]);
                    ps[nn] += 8;
                }
            }
            float thg[CNPW], axv[CNPW];
#pragma unroll
            for (int nn = 0; nn < CNPW; ++nn) {
                thg[nn] = A0[nn] + A1[nn];
                float cx = C0[nn] + C1[nn];
                cx += __shfl_down(cx, 32);
                cx += __shfl_down(cx, 16);
                axv[nn] = cx;
                if (lane < 16) t1x[(size_t)(wbase + nn) * XPAD + lane] = cx;
            }

            float xrow = xin[(size_t)wbase * XPAD + lane];             // nodes 0..3
            float xr4  = xin[(size_t)(wbase + 4) * XPAD + f16i];       // node 4
            float b0z = bx[0 * HID + lane] + bh[0 * HID + lane];
            float b0r = bx[1 * HID + lane] + bh[1 * HID + lane];
            float az[CNPW], ar[CNPW];
#pragma unroll
            for (int nn = 0; nn < CNPW; ++nn) { az[nn] = b0z; ar[nn] = b0r; }
#pragma unroll
            for (int i = 0; i < INF; ++i) {
                float4 w = Wx4[i * HID + lane];
#pragma unroll
                for (int nn = 0; nn < CNPW; ++nn) {
                    float xv = (nn < 4) ? bcast(xrow, nn * XPAD + i) : bcast(xr4, i);
                    float tv = bcast(axv[nn], i);
                    az[nn] = fmaf(xv, w.x, fmaf(tv, w.y, az[nn]));
                    ar[nn] = fmaf(xv, w.z, fmaf(tv, w.w, ar[nn]));
                }
            }
#pragma unroll 8
            for (int j = 0; j < HID; ++j) {
                float4 w = Wh4[j * HID + lane];
#pragma unroll
                for (int nn = 0; nn < CNPW; ++nn) {
                    float hj = bcast(h32[nn], j);
                    float tj = bcast(thg[nn], j);
                    az[nn] = fmaf(hj, w.x, fmaf(tj, w.y, az[nn]));
                    ar[nn] = fmaf(hj, w.z, fmaf(tj, w.w, ar[nn]));
                }
            }
#pragma unroll
            for (int nn = 0; nn < CNPW; ++nn) {
                int node = wbase + nn;
                float Z = 1.0f / (1.0f + __expf(-az[nn]));
                float R = 1.0f / (1.0f + __expf(-ar[nn]));
                zz[nn] = Z;
                hr16[(size_t)node * HID + lane] = __float2half(h32[nn] * R);
            }
        }
        __threadfence();
        grid.sync();

        // ---- phase B: hr-gather + cand + blend + head + next xin ----
        {
            int ps[CNPW];
            float A0[CNPW], A1[CNPW];
#pragma unroll
            for (int nn = 0; nn < CNPW; ++nn) {
                ps[nn] = ps0[nn];
                A0[nn] = 0.0f; A1[nn] = 0.0f;
            }
            while ((ps[0] < es0[0]) | (ps[1] < es0[1]) | (ps[2] < es0[2]) |
                   (ps[3] < es0[3]) | (ps[4] < es0[4])) {
#pragma unroll
                for (int nn = 0; nn < CNPW; ++nn) {
                    bool act = ps[nn] < es0[nn];
                    int q = act ? ps[nn] : 0;
                    float m = act ? 1.0f : 0.0f;
                    int2 q0 = pack[q],     q1 = pack[q + 1], q2 = pack[q + 2], q3 = pack[q + 3];
                    int2 q4 = pack[q + 4], q5 = pack[q + 5], q6 = pack[q + 6], q7 = pack[q + 7];
                    A0[nn] = fmaf(__int_as_float(q0.y) * m,
                                  __half2float(hr16[(size_t)q0.x * HID + lane]), A0[nn]);
                    A1[nn] = fmaf(__int_as_float(q1.y) * m,
                                  __half2float(hr16[(size_t)q1.x * HID + lane]), A1[nn]);
                    A0[nn] = fmaf(__int_as_float(q2.y) * m,
                                  __half2float(hr16[(size_t)q2.x * HID + lane]), A0[nn]);
                    A1[nn] = fmaf(__int_as_float(q3.y) * m,
                                  __half2float(hr16[(size_t)q3.x * HID + lane]), A1[nn]);
                    A0[nn] = fmaf(__int_as_float(q4.y) * m,
                                  __half2float(hr16[(size_t)q4.x * HID + lane]), A0[nn]);
                    A1[nn] = fmaf(__int_as_float(q5.y) * m,
                                  __half2float(hr16[(size_t)q5.x * HID + lane]), A1[nn]);
                    A0[nn] = fmaf(__int_as_float(q6.y) * m,
                                  __half2float(hr16[(size_t)q6.x * HID + lane]), A0[nn]);
                    A1[nn] = fmaf(__int_as_float(q7.y) * m,
                                  __half2float(hr16[(size_t)q7.x * HID + lane]), A1[nn]);
                    ps[nn] += 8;
                }
            }
            float thg[CNPW], hrv[CNPW];
#pragma unroll
            for (int nn = 0; nn < CNPW; ++nn) {
                thg[nn] = A0[nn] + A1[nn];
                hrv[nn] = __half2float(hr16[(size_t)(wbase + nn) * HID + lane]);
            }

            float xrow = xin[(size_t)wbase * XPAD + lane];
            float xr4  = xin[(size_t)(wbase + 4) * XPAD + f16i];
            float trow = t1x[(size_t)wbase * XPAD + lane];
            float tr4  = t1x[(size_t)(wbase + 4) * XPAD + f16i];
            float b0 = bx[2 * HID + lane] + bh[2 * HID + lane];
            float ah[CNPW];
#pragma unroll
            for (int nn = 0; nn < CNPW; ++nn) ah[nn] = b0;
#pragma unroll
            for (int i = 0; i < INF; ++i) {
                float2 w = Wx2[i * HID + lane];
#pragma unroll
                for (int nn = 0; nn < CNPW; ++nn) {
                    float xv = (nn < 4) ? bcast(xrow, nn * XPAD + i) : bcast(xr4, i);
                    float tv = (nn < 4) ? bcast(trow, nn * XPAD + i) : bcast(tr4, i);
                    ah[nn] = fmaf(xv, w.x, fmaf(tv, w.y, ah[nn]));
                }
            }
#pragma unroll 8
            for (int j = 0; j < HID; ++j) {
                float2 w = Wh2[j * HID + lane];
#pragma unroll
                for (int nn = 0; nn < CNPW; ++nn) {
                    float hj = bcast(hrv[nn], j);
                    float tj = bcast(thg[nn], j);
                    ah[nn] = fmaf(hj, w.x, fmaf(tj, w.y, ah[nn]));
                }
            }
            const float* Xcur = X_seq + (size_t)t * NN * INF;
            const float* Xnxt = X_seq + (size_t)(t + 1 < TSTEPS ? t + 1 : t) * NN * INF;
#pragma unroll
            for (int nn = 0; nn < CNPW; ++nn) {
                int node = wbase + nn;
                float Ht = tanh_safe(ah[nn]);
                float hnew = zz[nn] * h32[nn] + (1.0f - zz[nn]) * Ht;
                h32[nn] = hnew;
                h16[(size_t)node * HID + lane] = __float2half(hnew);
                float u0, u1, u2;
                {
                    float v0 = hnew * hw[lane * OUTF + 0];
                    float v1 = hnew * hw[lane * OUTF + 1];
                    float v2 = hnew * hw[lane * OUTF + 2];
                    for (int off = 32; off; off >>= 1) {
                        v0 += __shfl_down(v0, off);
                        v1 += __shfl_down(v1, off);
                        v2 += __shfl_down(v2, off);
                    }
                    u0 = bcast(v0, 0) + hb[0];
                    u1 = bcast(v1, 0) + hb[1];
                    u2 = bcast(v2, 0) + hb[2];
                }
                if (lane == 0) {
                    float* o = out + (size_t)t * NN * OUTF + (size_t)node * OUTF;
                    o[0] = u0; o[1] = u1; o[2] = u2;
                }
                if (t + 1 < TSTEPS) {
                    const float* x1r = Xnxt + (size_t)node * INF;
                    const float* x0r = Xcur + (size_t)node * INF;
                    float x1 = (lane < INF) ? x1r[lane] : 0.0f;
                    float x0v = (lane >= 3 && lane < 7) ? x0r[lane] : 0.0f;
                    float dt = bcast(x1, 6) - bcast(x0v, 6);
                    float inv = 1.0f / dt;
                    float c3 = bcast(x0v, 3), c4 = bcast(x0v, 4), c5 = bcast(x0v, 5);
                    float val;
                    if (lane < 3) val = x1;
                    else if (lane < 6) val = (lane == 3) ? u0 : (lane == 4) ? u1 : u2;
                    else if (lane < 8) val = x1;
                    else if (lane < 11) {
                        float uu = (lane == 8) ? u0 : (lane == 9) ? u1 : u2;
                        float cc = (lane == 8) ? c3 : (lane == 9) ? c4 : c5;
                        val = (uu - cc) * inv;
                    } else val = 0.0f;
                    if (lane < XPAD) {
                        xin[(size_t)node * XPAD + lane] = val;
                        xin16[(size_t)node * XPAD + lane] = __float2half(val);
                    }
                }
            }
        }
        if (t + 1 < TSTEPS) {
            __threadfence();
            grid.sync();
        }
    }
}

extern "C" void kernel_launch(void* const* d_in, const int* in_sizes, int n_in,
                              void* d_out, int out_size, void* d_ws, size_t ws_size,
                              hipStream_t stream) {
    const float* X_seq = (const float*)d_in[0];
    const int* edge = (const int*)d_in[1];
    const float* Wx = (const float*)d_in[2];
    const float* bx = (const float*)d_in[3];
    const float* Wh = (const float*)d_in[4];
    const float* bh = (const float*)d_in[5];
    const float* head_W = (const float*)d_in[6];
    const float* head_b = (const float*)d_in[7];
    float* out = (float*)d_out;

    const int* src = edge;
    const int* dst = edge + NE;

    // ---- workspace layout ----
    float* ws = (float*)d_ws;
    float4* Wh4g = (float4*)ws;                          // 4096 f4
    float4* Wx4g = (float4*)(ws + 16384);                // 704 f4
    float2* Wh2c = (float2*)(ws + 19200);                // 4096 f2
    float2* Wx2c = (float2*)(ws + 27392);                // 704 f2
    float* fbase = ws + 28800;
    float* xin  = fbase;                                 // N*16
    float* t1x  = xin + (size_t)NN * XPAD;               // N*16
    float* h    = t1x + (size_t)NN * XPAD;               // N*64 (fallback only)
    int* degi     = (int*)(h + (size_t)NN * HID);        // N
    int* indeg    = degi + NN;                           // N
    int* rowstart = indeg + NN;                          // N+2
    int* cursor   = rowstart + NN + 2;                   // N
    int* bsum     = cursor + NN;                         // 128
    int* boff     = bsum + 128;                          // 128
    int2* pack    = (int2*)(boff + 128);                 // EPMAX int2
    __half* h16   = (__half*)(pack + EPMAX);             // N*64
    __half* hr16  = h16 + (size_t)NN * HID;              // N*64
    __half* Zb16  = hr16 + (size_t)NN * HID;             // N*64 (fallback only)
    __half* xin16 = Zb16 + (size_t)NN * HID;             // N*16

    // ---- setup (once per call) ----
    hipMemsetAsync(degi, 0, 2 * NN * sizeof(int), stream);
    hipMemsetAsync(pack, 0, (size_t)EPMAX * sizeof(int2), stream);
    k_cnt<<<(NE + 255) / 256, 256, 0, stream>>>(src, dst, degi, indeg, NE);
    k_scanA<<<NB, 256, 0, stream>>>(indeg, rowstart, bsum, NN);
    k_scanB<<<1, 128, 0, stream>>>(bsum, boff, NB);
    k_scanC<<<NB, 256, 0, stream>>>(indeg, rowstart, boff, cursor, NN);
    k_fill<<<(NE + 255) / 256, 256, 0, stream>>>(src, dst, degi, cursor, pack, NE);
    k_init<<<(NN * HID + 255) / 256, 256, 0, stream>>>(
        Wh, Wx, Wh4g, Wh2c, Wx4g, Wx2c, h, h16, X_seq, xin, xin16);

    // ---- try cooperative mega-kernel; verified fallback otherwise ----
    int maxB = 0;
    hipError_t oe = hipOccupancyMaxActiveBlocksPerMultiprocessor(&maxB, k_loop, 256, 0);
    bool coop_ok = (oe == hipSuccess) && (maxB * 256 >= CNBLK);
    if (coop_ok) {
        const int* rowstart_c = rowstart;
        const int2* pack_c = pack;
        const float* X_c = X_seq;
        float* xin_c = xin;
        __half* xin16_c = xin16;
        __half* h16_c = h16;
        __half* hr16_c = hr16;
        float* t1x_c = t1x;
        const float4* Wx4_c = Wx4g;
        const float2* Wx2_c = Wx2c;
        const float* bx_c = bx;
        const float4* Wh4_c = Wh4g;
        const float2* Wh2_c = Wh2c;
        const float* bh_c = bh;
        const float* hw_c = head_W;
        const float* hb_c = head_b;
        float* out_c = out;
        void* kargs[] = {
            (void*)&rowstart_c, (void*)&pack_c, (void*)&X_c,
            (void*)&xin_c, (void*)&xin16_c, (void*)&h16_c, (void*)&hr16_c,
            (void*)&t1x_c,
            (void*)&Wx4_c, (void*)&Wx2_c, (void*)&bx_c,
            (void*)&Wh4_c, (void*)&Wh2_c, (void*)&bh_c,
            (void*)&hw_c, (void*)&hb_c, (void*)&out_c
        };
        hipError_t le = hipLaunchCooperativeKernel((const void*)k_loop, dim3(CNBLK),
                                                   dim3(256), kargs, 0, stream);
        coop_ok = (le == hipSuccess);
    }
    if (!coop_ok) {
        // proven round-15 path
        const int fused_grid = (NN + 4 * NPW - 1) / (4 * NPW);  // 1250
        for (int t = 0; t < TSTEPS; ++t) {
            k_gz<<<fused_grid, 256, 0, stream>>>(rowstart, pack, xin, xin16, h16,
                                                 Wx4g, bx, Wh4g, bh,
                                                 t1x, Zb16, hr16, NN);
            const float* Xcur = X_seq + (size_t)t * NN * INF;
            const float* Xnxt = (t + 1 < TSTEPS) ? X_seq + (size_t)(t + 1) * NN * INF : X_seq;
            k_gc<<<fused_grid, 256, 0, stream>>>(rowstart, pack, xin, t1x, h, h16, hr16,
                                                 Wx2c, bx, Wh2c, bh, Zb16,
                                                 head_W, head_b,
                                                 out + (size_t)t * NN * OUTF,
                                                 Xcur, Xnxt, xin, xin16,
                                                 (t + 1 == TSTEPS) ? 1 : 0, NN);
        }
    }
}

// Round 17
// 434.116 us; speedup vs baseline: 1.0019x; 1.0019x over previous
//
#include <hip/hip_runtime.h>
#include <hip/hip_fp16.h>
#include <math.h>

#define TSTEPS 6
#define NN 20000
#define NE 320000
#define INF 11
#define XPAD 16
#define HID 64
#define OUTF 3
#define NPW 4                     // nodes per wave in fused kernels
#define EPMAX (NE + 7 * NN)       // CSR slots after pad-to-8
#define NB ((NN + 255) / 256)     // scan blocks = 79

__device__ __forceinline__ float bcast(float v, int l) {
    return __uint_as_float(__builtin_amdgcn_readlane(__float_as_uint(v), l));
}

__device__ __forceinline__ float tanh_safe(float a) {
    float e2 = __expf(-2.0f * fabsf(a));
    float t = (1.0f - e2) / (1.0f + e2);
    return copysignf(t, a);
}

// ---------------- setup kernels (once per call) ----------------

__global__ void k_cnt(const int* __restrict__ src, const int* __restrict__ dst,
                      int* __restrict__ degi, int* __restrict__ indeg, int E) {
    int e = blockIdx.x * blockDim.x + threadIdx.x;
    if (e >= E) return;
    atomicAdd(&degi[src[e]], 1);
    atomicAdd(&indeg[dst[e]], 1);
}

// scanA: per-block inclusive scan of padded indeg into part, block totals to bsum
__global__ __launch_bounds__(256) void k_scanA(const int* __restrict__ indeg,
                                               int* __restrict__ part,
                                               int* __restrict__ bsum, int n) {
    int idx = blockIdx.x * 256 + threadIdx.x;
    int lane = threadIdx.x & 63, wv = threadIdx.x >> 6;
    int v = (idx < n) ? ((indeg[idx] + 7) & ~7) : 0;
#pragma unroll
    for (int off = 1; off < 64; off <<= 1) {
        int t = __shfl_up(v, off);
        if (lane >= off) v += t;
    }
    __shared__ int wsum[4];
    if (lane == 63) wsum[wv] = v;
    __syncthreads();
    int add = 0;
    for (int w = 0; w < wv; ++w) add += wsum[w];
    v += add;
    if (idx < n) part[idx] = v;
    if (threadIdx.x == 255) bsum[blockIdx.x] = v;
}

__global__ __launch_bounds__(128) void k_scanB(const int* __restrict__ bsum,
                                               int* __restrict__ boff, int nb) {
    int tid = threadIdx.x;
    int lane = tid & 63, wv = tid >> 6;
    int orig = (tid < nb) ? bsum[tid] : 0;
    int v = orig;
#pragma unroll
    for (int off = 1; off < 64; off <<= 1) {
        int t = __shfl_up(v, off);
        if (lane >= off) v += t;
    }
    __shared__ int w0;
    if (lane == 63 && wv == 0) w0 = v;
    __syncthreads();
    if (wv == 1) v += w0;
    if (tid < nb) boff[tid] = v - orig;  // exclusive
}

__global__ __launch_bounds__(256) void k_scanC(const int* __restrict__ indeg,
                                               int* __restrict__ part,
                                               const int* __restrict__ boff,
                                               int* __restrict__ cursor, int n) {
    int idx = blockIdx.x * 256 + threadIdx.x;
    if (idx >= n) return;
    int pd = (indeg[idx] + 7) & ~7;
    int incl = part[idx] + boff[blockIdx.x];
    int excl = incl - pd;
    part[idx] = excl;      // part aliases rowstart
    cursor[idx] = excl;
    if (idx == n - 1) part[n] = incl;
}

// fill CSR: packed {src, w} int2, bucketed by dst; norm computed inline from degi
__global__ void k_fill(const int* __restrict__ src, const int* __restrict__ dst,
                       const int* __restrict__ degi, int* __restrict__ cursor,
                       int2* __restrict__ pack, int E) {
    int e = blockIdx.x * blockDim.x + threadIdx.x;
    if (e >= E) return;
    int s = src[e], d = dst[e];
    float ds = (float)degi[s];
    float dd = (float)degi[d];
    float ns = ds > 0.0f ? rsqrtf(fmaxf(ds, 1.0f)) : 0.0f;
    float nd = dd > 0.0f ? rsqrtf(fmaxf(dd, 1.0f)) : 0.0f;
    int pos = atomicAdd(&cursor[d], 1);
    int2 v;
    v.x = s;
    v.y = __float_as_int(-ns * nd);
    pack[pos] = v;
}

// merged init: weight packing + h/h16 zero + t0 xin build (disjoint index ranges)
__global__ void k_init(const float* __restrict__ Wh, const float* __restrict__ Wx,
                       float4* __restrict__ Wh4, float2* __restrict__ Wh2,
                       float4* __restrict__ Wx4, float2* __restrict__ Wx2,
                       float* __restrict__ h, __half* __restrict__ h16,
                       const float* __restrict__ Xt, float* __restrict__ xin,
                       __half* __restrict__ xin16) {
    int idx = blockIdx.x * blockDim.x + threadIdx.x;
    if (idx < NN * HID) { h[idx] = 0.0f; h16[idx] = __float2half(0.0f); }
    if (idx < HID * HID) {
        int j = idx >> 6, f = idx & 63;
        float4 v4;
        v4.x = Wh[((0 * 2 + 0) * HID + j) * HID + f];
        v4.y = Wh[((0 * 2 + 1) * HID + j) * HID + f];
        v4.z = Wh[((1 * 2 + 0) * HID + j) * HID + f];
        v4.w = Wh[((1 * 2 + 1) * HID + j) * HID + f];
        Wh4[idx] = v4;
        float2 v2;
        v2.x = Wh[((2 * 2 + 0) * HID + j) * HID + f];
        v2.y = Wh[((2 * 2 + 1) * HID + j) * HID + f];
        Wh2[idx] = v2;
    } else if (idx < HID * HID + INF * HID) {
        int k = idx - HID * HID;
        int i = k >> 6, f = k & 63;
        float4 v4;
        v4.x = Wx[((0 * 2 + 0) * INF + i) * HID + f];
        v4.y = Wx[((0 * 2 + 1) * INF + i) * HID + f];
        v4.z = Wx[((1 * 2 + 0) * INF + i) * HID + f];
        v4.w = Wx[((1 * 2 + 1) * INF + i) * HID + f];
        Wx4[k] = v4;
        float2 v2;
        v2.x = Wx[((2 * 2 + 0) * INF + i) * HID + f];
        v2.y = Wx[((2 * 2 + 1) * INF + i) * HID + f];
        Wx2[k] = v2;
    }
    if (idx < NN) {
        const float* xt = Xt + (size_t)idx * INF;
        float* xo = xin + (size_t)idx * XPAD;
        __half* xh = xin16 + (size_t)idx * XPAD;
#pragma unroll
        for (int k = 0; k < INF; ++k) { float v = xt[k]; xo[k] = v; xh[k] = __float2half(v); }
#pragma unroll
        for (int k = INF; k < XPAD; ++k) { xo[k] = 0.0f; xh[k] = __float2half(0.0f); }
    }
}

// ---------------- fused per-timestep kernels ----------------

// gz: interleaved 4-node {h-gather + x-gather} + Z/R dense. No LDS.
__global__ __launch_bounds__(256) void k_gz(
    const int* __restrict__ rowstart, const int2* __restrict__ pack,
    const float* __restrict__ xin, const __half* __restrict__ xin16,
    const __half* __restrict__ h16,
    const float4* __restrict__ Wx4, const float* __restrict__ bx,
    const float4* __restrict__ Wh4, const float* __restrict__ bh,
    float* __restrict__ t1x, __half* __restrict__ Zb16,
    __half* __restrict__ hr16, int n) {
    int wid = __builtin_amdgcn_readfirstlane(
        (int)((blockIdx.x * blockDim.x + threadIdx.x) >> 6));
    int wbase = wid * NPW;
    int lane = threadIdx.x & 63;
    int f16i = lane & 15, eo = lane >> 4;
    if (wbase >= n) return;

    int ps[NPW], es[NPW];
    float A0[NPW], A1[NPW], C0[NPW], C1[NPW];
    float thg[NPW], axv[NPW], hv[NPW];
#pragma unroll
    for (int nn = 0; nn < NPW; ++nn) {
        int node = wbase + nn;
        ps[nn] = rowstart[node];
        es[nn] = rowstart[node + 1];    // (es-ps) % 8 == 0 (CSR padded)
        hv[nn] = __half2float(h16[(size_t)node * HID + lane]);
        A0[nn] = 0.0f; A1[nn] = 0.0f; C0[nn] = 0.0f; C1[nn] = 0.0f;
    }
    while ((ps[0] < es[0]) | (ps[1] < es[1]) | (ps[2] < es[2]) | (ps[3] < es[3])) {
#pragma unroll
        for (int nn = 0; nn < NPW; ++nn) {
            bool act = ps[nn] < es[nn];
            int q = act ? ps[nn] : 0;       // inactive: reload batch 0 with m=0
            float m = act ? 1.0f : 0.0f;
            int2 q0 = pack[q],     q1 = pack[q + 1], q2 = pack[q + 2], q3 = pack[q + 3];
            int2 q4 = pack[q + 4], q5 = pack[q + 5], q6 = pack[q + 6], q7 = pack[q + 7];
            float w0 = __int_as_float(q0.y) * m, w1 = __int_as_float(q1.y) * m;
            float w2 = __int_as_float(q2.y) * m, w3 = __int_as_float(q3.y) * m;
            float w4 = __int_as_float(q4.y) * m, w5 = __int_as_float(q5.y) * m;
            float w6 = __int_as_float(q6.y) * m, w7 = __int_as_float(q7.y) * m;
            A0[nn] = fmaf(w0, __half2float(h16[(size_t)q0.x * HID + lane]), A0[nn]);
            A1[nn] = fmaf(w1, __half2float(h16[(size_t)q1.x * HID + lane]), A1[nn]);
            A0[nn] = fmaf(w2, __half2float(h16[(size_t)q2.x * HID + lane]), A0[nn]);
            A1[nn] = fmaf(w3, __half2float(h16[(size_t)q3.x * HID + lane]), A1[nn]);
            A0[nn] = fmaf(w4, __half2float(h16[(size_t)q4.x * HID + lane]), A0[nn]);
            A1[nn] = fmaf(w5, __half2float(h16[(size_t)q5.x * HID + lane]), A1[nn]);
            A0[nn] = fmaf(w6, __half2float(h16[(size_t)q6.x * HID + lane]), A0[nn]);
            A1[nn] = fmaf(w7, __half2float(h16[(size_t)q7.x * HID + lane]), A1[nn]);
            // x-gather: lane-group eo handles edges 2*eo, 2*eo+1 (direct loads)
            int2 x0 = pack[q + 2 * eo], x1 = pack[q + 2 * eo + 1];
            C0[nn] = fmaf(__int_as_float(x0.y) * m,
                          __half2float(xin16[(size_t)x0.x * XPAD + f16i]), C0[nn]);
            C1[nn] = fmaf(__int_as_float(x1.y) * m,
                          __half2float(xin16[(size_t)x1.x * XPAD + f16i]), C1[nn]);
            ps[nn] += 8;
        }
    }
#pragma unroll
    for (int nn = 0; nn < NPW; ++nn) {
        thg[nn] = A0[nn] + A1[nn];
        float cx = C0[nn] + C1[nn];
        cx += __shfl_down(cx, 32);
        cx += __shfl_down(cx, 16);
        axv[nn] = cx;  // valid lanes 0..15
    }
#pragma unroll
    for (int nn = 0; nn < NPW; ++nn)
        if (lane < 16) t1x[(size_t)(wbase + nn) * XPAD + lane] = axv[nn];

    // dense Z/R
    float xrow = xin[(size_t)wbase * XPAD + lane];
    float b0z = bx[0 * HID + lane] + bh[0 * HID + lane];
    float b0r = bx[1 * HID + lane] + bh[1 * HID + lane];
    float az[NPW], ar[NPW];
#pragma unroll
    for (int nn = 0; nn < NPW; ++nn) { az[nn] = b0z; ar[nn] = b0r; }
#pragma unroll
    for (int i = 0; i < INF; ++i) {
        float4 w = Wx4[i * HID + lane];
#pragma unroll
        for (int nn = 0; nn < NPW; ++nn) {
            float xv = bcast(xrow, nn * XPAD + i);
            float tv = bcast(axv[nn], i);
            az[nn] = fmaf(xv, w.x, fmaf(tv, w.y, az[nn]));
            ar[nn] = fmaf(xv, w.z, fmaf(tv, w.w, ar[nn]));
        }
    }
#pragma unroll 8
    for (int j = 0; j < HID; ++j) {
        float4 w = Wh4[j * HID + lane];
#pragma unroll
        for (int nn = 0; nn < NPW; ++nn) {
            float hj = bcast(hv[nn], j);
            float tj = bcast(thg[nn], j);
            az[nn] = fmaf(hj, w.x, fmaf(tj, w.y, az[nn]));
            ar[nn] = fmaf(hj, w.z, fmaf(tj, w.w, ar[nn]));
        }
    }
#pragma unroll
    for (int nn = 0; nn < NPW; ++nn) {
        int node = wbase + nn;
        float Z = 1.0f / (1.0f + __expf(-az[nn]));
        float R = 1.0f / (1.0f + __expf(-ar[nn]));
        Zb16[(size_t)node * HID + lane] = __float2half(Z);
        hr16[(size_t)node * HID + lane] = __float2half(hv[nn] * R);
    }
}

// gc: interleaved 4-node hr-gather + candidate + blend + head + next xin. No LDS.
__global__ __launch_bounds__(256) void k_gc(
    const int* __restrict__ rowstart, const int2* __restrict__ pack,
    const float* __restrict__ xin, const float* __restrict__ t1x,
    float* __restrict__ h, __half* __restrict__ h16,
    const __half* __restrict__ hr16,
    const float2* __restrict__ Wx2, const float* __restrict__ bx,
    const float2* __restrict__ Wh2, const float* __restrict__ bh,
    const __half* __restrict__ Zb16,
    const float* __restrict__ hw, const float* __restrict__ hb,
    float* __restrict__ out,
    const float* __restrict__ Xcur, const float* __restrict__ Xnxt,
    float* __restrict__ xin_w, __half* __restrict__ xin16_w,
    int last, int n) {
    int wid = __builtin_amdgcn_readfirstlane(
        (int)((blockIdx.x * blockDim.x + threadIdx.x) >> 6));
    int wbase = wid * NPW;
    int lane = threadIdx.x & 63;
    if (wbase >= n) return;

    int ps[NPW], es[NPW];
    float A0[NPW], A1[NPW];
    float thg[NPW], hrv[NPW];
#pragma unroll
    for (int nn = 0; nn < NPW; ++nn) {
        int node = wbase + nn;
        ps[nn] = rowstart[node];
        es[nn] = rowstart[node + 1];
        hrv[nn] = __half2float(hr16[(size_t)node * HID + lane]);
        A0[nn] = 0.0f; A1[nn] = 0.0f;
    }
    while ((ps[0] < es[0]) | (ps[1] < es[1]) | (ps[2] < es[2]) | (ps[3] < es[3])) {
#pragma unroll
        for (int nn = 0; nn < NPW; ++nn) {
            bool act = ps[nn] < es[nn];
            int q = act ? ps[nn] : 0;
            float m = act ? 1.0f : 0.0f;
            int2 q0 = pack[q],     q1 = pack[q + 1], q2 = pack[q + 2], q3 = pack[q + 3];
            int2 q4 = pack[q + 4], q5 = pack[q + 5], q6 = pack[q + 6], q7 = pack[q + 7];
            A0[nn] = fmaf(__int_as_float(q0.y) * m,
                          __half2float(hr16[(size_t)q0.x * HID + lane]), A0[nn]);
            A1[nn] = fmaf(__int_as_float(q1.y) * m,
                          __half2float(hr16[(size_t)q1.x * HID + lane]), A1[nn]);
            A0[nn] = fmaf(__int_as_float(q2.y) * m,
                          __half2float(hr16[(size_t)q2.x * HID + lane]), A0[nn]);
            A1[nn] = fmaf(__int_as_float(q3.y) * m,
                          __half2float(hr16[(size_t)q3.x * HID + lane]), A1[nn]);
            A0[nn] = fmaf(__int_as_float(q4.y) * m,
                          __half2float(hr16[(size_t)q4.x * HID + lane]), A0[nn]);
            A1[nn] = fmaf(__int_as_float(q5.y) * m,
                          __half2float(hr16[(size_t)q5.x * HID + lane]), A1[nn]);
            A0[nn] = fmaf(__int_as_float(q6.y) * m,
                          __half2float(hr16[(size_t)q6.x * HID + lane]), A0[nn]);
            A1[nn] = fmaf(__int_as_float(q7.y) * m,
                          __half2float(hr16[(size_t)q7.x * HID + lane]), A1[nn]);
            ps[nn] += 8;
        }
    }
#pragma unroll
    for (int nn = 0; nn < NPW; ++nn) thg[nn] = A0[nn] + A1[nn];

    float xrow = xin[(size_t)wbase * XPAD + lane];
    float trow = t1x[(size_t)wbase * XPAD + lane];
    float b0 = bx[2 * HID + lane] + bh[2 * HID + lane];
    float ah[NPW];
#pragma unroll
    for (int nn = 0; nn < NPW; ++nn) ah[nn] = b0;
#pragma unroll
    for (int i = 0; i < INF; ++i) {
        float2 w = Wx2[i * HID + lane];
#pragma unroll
        for (int nn = 0; nn < NPW; ++nn) {
            float xv = bcast(xrow, nn * XPAD + i);
            float tv = bcast(trow, nn * XPAD + i);
            ah[nn] = fmaf(xv, w.x, fmaf(tv, w.y, ah[nn]));
        }
    }
#pragma unroll 8
    for (int j = 0; j < HID; ++j) {
        float2 w = Wh2[j * HID + lane];
#pragma unroll
        for (int nn = 0; nn < NPW; ++nn) {
            float hj = bcast(hrv[nn], j);
            float tj = bcast(thg[nn], j);
            ah[nn] = fmaf(hj, w.x, fmaf(tj, w.y, ah[nn]));
        }
    }
#pragma unroll
    for (int nn = 0; nn < NPW; ++nn) {
        int node = wbase + nn;
        float Ht = tanh_safe(ah[nn]);
        float z = __half2float(Zb16[(size_t)node * HID + lane]);
        float hvv = h[(size_t)node * HID + lane];
        float hnew = z * hvv + (1.0f - z) * Ht;
        h[(size_t)node * HID + lane] = hnew;
        h16[(size_t)node * HID + lane] = __float2half(hnew);
        float u0, u1, u2;
        {
            float v0 = hnew * hw[lane * OUTF + 0];
            float v1 = hnew * hw[lane * OUTF + 1];
            float v2 = hnew * hw[lane * OUTF + 2];
            for (int off = 32; off; off >>= 1) {
                v0 += __shfl_down(v0, off);
                v1 += __shfl_down(v1, off);
                v2 += __shfl_down(v2, off);
            }
            u0 = bcast(v0, 0) + hb[0];
            u1 = bcast(v1, 0) + hb[1];
            u2 = bcast(v2, 0) + hb[2];
        }
        if (lane == 0) {
            float* o = out + (size_t)node * OUTF;
            o[0] = u0; o[1] = u1; o[2] = u2;
        }
        if (!last) {
            const float* x1r = Xnxt + (size_t)node * INF;
            const float* x0r = Xcur + (size_t)node * INF;
            float x1 = (lane < INF) ? x1r[lane] : 0.0f;
            float x0v = (lane >= 3 && lane < 7) ? x0r[lane] : 0.0f;
            float dt = bcast(x1, 6) - bcast(x0v, 6);
            float inv = 1.0f / dt;
            float c3 = bcast(x0v, 3), c4 = bcast(x0v, 4), c5 = bcast(x0v, 5);
            float val;
            if (lane < 3) val = x1;
            else if (lane < 6) val = (lane == 3) ? u0 : (lane == 4) ? u1 : u2;
            else if (lane < 8) val = x1;
            else if (lane < 11) {
                float uu = (lane == 8) ? u0 : (lane == 9) ? u1 : u2;
                float cc = (lane == 8) ? c3 : (lane == 9) ? c4 : c5;
                val = (uu - cc) * inv;
            } else val = 0.0f;
            if (lane < XPAD) {
                xin_w[(size_t)node * XPAD + lane] = val;
                xin16_w[(size_t)node * XPAD + lane] = __float2half(val);
            }
        }
    }
}

extern "C" void kernel_launch(void* const* d_in, const int* in_sizes, int n_in,
                              void* d_out, int out_size, void* d_ws, size_t ws_size,
                              hipStream_t stream) {
    const float* X_seq = (const float*)d_in[0];
    const int* edge = (const int*)d_in[1];
    const float* Wx = (const float*)d_in[2];
    const float* bx = (const float*)d_in[3];
    const float* Wh = (const float*)d_in[4];
    const float* bh = (const float*)d_in[5];
    const float* head_W = (const float*)d_in[6];
    const float* head_b = (const float*)d_in[7];
    float* out = (float*)d_out;

    const int* src = edge;
    const int* dst = edge + NE;

    // ---- workspace layout ----
    float* ws = (float*)d_ws;
    float4* Wh4g = (float4*)ws;                          // 4096 f4
    float4* Wx4g = (float4*)(ws + 16384);                // 704 f4
    float2* Wh2c = (float2*)(ws + 19200);                // 4096 f2
    float2* Wx2c = (float2*)(ws + 27392);                // 704 f2
    float* fbase = ws + 28800;
    float* xin  = fbase;                                 // N*16
    float* t1x  = xin + (size_t)NN * XPAD;               // N*16
    float* h    = t1x + (size_t)NN * XPAD;               // N*64
    int* degi     = (int*)(h + (size_t)NN * HID);        // N
    int* indeg    = degi + NN;                           // N
    int* rowstart = indeg + NN;                          // N+2
    int* cursor   = rowstart + NN + 2;                   // N
    int* bsum     = cursor + NN;                         // 128
    int* boff     = bsum + 128;                          // 128
    int2* pack    = (int2*)(boff + 128);                 // EPMAX int2
    __half* h16   = (__half*)(pack + EPMAX);             // N*64
    __half* hr16  = h16 + (size_t)NN * HID;              // N*64
    __half* Zb16  = hr16 + (size_t)NN * HID;             // N*64
    __half* xin16 = Zb16 + (size_t)NN * HID;             // N*16

    // ---- setup (once per call): 2 memsets + 6 kernels ----
    hipMemsetAsync(degi, 0, 2 * NN * sizeof(int), stream);         // degi + indeg
    hipMemsetAsync(pack, 0, (size_t)EPMAX * sizeof(int2), stream); // zero pad slots
    k_cnt<<<(NE + 255) / 256, 256, 0, stream>>>(src, dst, degi, indeg, NE);
    k_scanA<<<NB, 256, 0, stream>>>(indeg, rowstart, bsum, NN);
    k_scanB<<<1, 128, 0, stream>>>(bsum, boff, NB);
    k_scanC<<<NB, 256, 0, stream>>>(indeg, rowstart, boff, cursor, NN);
    k_fill<<<(NE + 255) / 256, 256, 0, stream>>>(src, dst, degi, cursor, pack, NE);
    k_init<<<(NN * HID + 255) / 256, 256, 0, stream>>>(
        Wh, Wx, Wh4g, Wh2c, Wx4g, Wx2c, h, h16, X_seq, xin, xin16);

    const int fused_grid = (NN + 4 * NPW - 1) / (4 * NPW);  // 1250

    for (int t = 0; t < TSTEPS; ++t) {
        k_gz<<<fused_grid, 256, 0, stream>>>(rowstart, pack, xin, xin16, h16,
                                             Wx4g, bx, Wh4g, bh,
                                             t1x, Zb16, hr16, NN);

        const float* Xcur = X_seq + (size_t)t * NN * INF;
        const float* Xnxt = (t + 1 < TSTEPS) ? X_seq + (size_t)(t + 1) * NN * INF : X_seq;
        k_gc<<<fused_grid, 256, 0, stream>>>(rowstart, pack, xin, t1x, h, h16, hr16,
                                             Wx2c, bx, Wh2c, bh, Zb16,
                                             head_W, head_b,
                                             out + (size_t)t * NN * OUTF,
                                             Xcur, Xnxt, xin, xin16,
                                             (t + 1 == TSTEPS) ? 1 : 0, NN);
    }
}